// Round 1
// baseline (216.212 us; speedup 1.0000x reference)
//
#include <hip/hip_runtime.h>
#include <stdint.h>

#define V3 110592        // 48*48*48
#define PLANE 2304       // 48*48
#define NI 32
#define NO 64
#define NP 10
#define KTOT 320         // NI*NP
#define LSTR 24          // padded LDS row stride (floats): rows 0,24,48,72 -> 2-way max (free)

typedef unsigned short ushort_t;
typedef __attribute__((ext_vector_type(8))) short short8v;
typedef __attribute__((ext_vector_type(4))) float float4v;

__device__ __forceinline__ ushort_t f2bf(float f) {
  uint32_t u = __float_as_uint(f);
  u += 0x7FFFu + ((u >> 16) & 1u);   // round-to-nearest-even
  return (ushort_t)(u >> 16);
}

// ---------- prep: Abf[m][k] = bf16(Y0 * weight[m*320 + k]) (weight layout == [o][i*10+p]) ----------
__global__ void prep_kernel(const float* __restrict__ w, ushort_t* __restrict__ Abf) {
  int idx = blockIdx.x * 256 + threadIdx.x;
  if (idx < NO * KTOT) Abf[idx] = f2bf(0.28209479177387814f * w[idx]);
}

// ---------- pass 1: separable shell sums ----------
// S[k = i*10+p][n_local = (d-d0)*2304 + h*48 + w]  (bf16), per (b, d-chunk)
__device__ __forceinline__ void stage_plane(float* pl, const float* xi, int p,
                                            int h0, int w0, int tid) {
  __syncthreads();
  for (int s = tid; s < 20 * 20; s += 256) {
    int lh = s / 20, lw = s % 20;
    int gh = h0 - 2 + lh, gw = w0 - 2 + lw;
    float v = 0.f;
    if (p >= 0 && p < 48 && gh >= 0 && gh < 48 && gw >= 0 && gw < 48)
      v = xi[(size_t)p * PLANE + gh * 48 + gw];
    pl[lh * LSTR + lw] = v;
  }
  __syncthreads();
}

// 2D (x,y) partial shell sums of one plane, classes q = dx^2+dy^2 in {0,1,2,4,5,8}
__device__ __forceinline__ void compute_B(const float* pl, int hh, int ww, float Bn[6]) {
  float a0[5], a1[5], a2[5];
#pragma unroll
  for (int dy = 0; dy < 5; ++dy) {
    const float* row = pl + (hh + dy) * LSTR + ww;
    float r0 = row[0], r1 = row[1], r2 = row[2], r3 = row[3], r4 = row[4];
    a0[dy] = r2;            // dx^2 = 0
    a1[dy] = r1 + r3;       // dx^2 = 1
    a2[dy] = r0 + r4;       // dx^2 = 4
  }
  Bn[0] = a0[2];                                   // q=0
  Bn[1] = a1[2] + a0[1] + a0[3];                   // q=1
  Bn[2] = a1[1] + a1[3];                           // q=2
  Bn[3] = a2[2] + a0[0] + a0[4];                   // q=4
  Bn[4] = a2[1] + a2[3] + a1[0] + a1[4];           // q=5
  Bn[5] = a2[0] + a2[4];                           // q=8
}

__global__ __launch_bounds__(256) void shell_kernel(const float* __restrict__ xb,
                                                    ushort_t* __restrict__ S,
                                                    int d0, int Nch) {
  __shared__ float pl[20 * LSTR];
  const int tid = threadIdx.x;
  const int i = blockIdx.z;
  const int ht = blockIdx.x / 3, wt = blockIdx.x % 3;
  const int h0 = ht * 16, w0 = wt * 16;
  const int d_start = d0 + blockIdx.y * 12;
  const float* xi = xb + (size_t)i * V3;
  const int hh = tid >> 4, ww = tid & 15;

  // rolling window: B[q][j] holds plane (d - 3 + j) entering iteration d
  float B[6][5];
#pragma unroll
  for (int q = 0; q < 6; ++q)
#pragma unroll
    for (int j = 0; j < 5; ++j) B[q][j] = 0.f;

  {
    float Bn[6];
    stage_plane(pl, xi, d_start - 2, h0, w0, tid);
    compute_B(pl, hh, ww, Bn);
#pragma unroll
    for (int q = 0; q < 6; ++q) B[q][1] = Bn[q];
    stage_plane(pl, xi, d_start - 1, h0, w0, tid);
    compute_B(pl, hh, ww, Bn);
#pragma unroll
    for (int q = 0; q < 6; ++q) B[q][2] = Bn[q];
    stage_plane(pl, xi, d_start, h0, w0, tid);
    compute_B(pl, hh, ww, Bn);
#pragma unroll
    for (int q = 0; q < 6; ++q) B[q][3] = Bn[q];
    stage_plane(pl, xi, d_start + 1, h0, w0, tid);
    compute_B(pl, hh, ww, Bn);
#pragma unroll
    for (int q = 0; q < 6; ++q) B[q][4] = Bn[q];
  }

  for (int d = d_start; d < d_start + 12; ++d) {
#pragma unroll
    for (int q = 0; q < 6; ++q) {
      B[q][0] = B[q][1]; B[q][1] = B[q][2]; B[q][2] = B[q][3]; B[q][3] = B[q][4];
    }
    stage_plane(pl, xi, d + 2, h0, w0, tid);
    float Bn[6];
    compute_B(pl, hh, ww, Bn);
#pragma unroll
    for (int q = 0; q < 6; ++q) B[q][4] = Bn[q];

    // 3D shells r^2 in {0,1,2,3,4,5,6,8,9,12}; slot 2+dz holds plane d+dz
    float Sv[10];
    Sv[0] = B[0][2];
    Sv[1] = B[1][2] + B[0][1] + B[0][3];
    Sv[2] = B[2][2] + B[1][1] + B[1][3];
    Sv[3] = B[2][1] + B[2][3];
    Sv[4] = B[3][2] + B[0][0] + B[0][4];
    Sv[5] = B[4][2] + B[3][1] + B[3][3] + B[1][0] + B[1][4];
    Sv[6] = B[4][1] + B[4][3] + B[2][0] + B[2][4];
    Sv[7] = B[5][2] + B[3][0] + B[3][4];
    Sv[8] = B[5][1] + B[5][3] + B[4][0] + B[4][4];
    Sv[9] = B[5][0] + B[5][4];

    size_t n_local = (size_t)(d - d0) * PLANE + (size_t)(h0 + hh) * 48 + (w0 + ww);
    ushort_t* sp = S + (size_t)(i * NP) * Nch + n_local;
#pragma unroll
    for (int p = 0; p < 10; ++p) sp[(size_t)p * Nch] = f2bf(Sv[p]);
  }
}

// ---------- pass 2: out[m][v] = sum_k A[m][k]*S[k][n] + bias[m], bf16 MFMA ----------
#define ALD 328   // padded LDS row stride (elems): 164 dwords % 32 = 4 -> 2-way (free)
__global__ __launch_bounds__(256) void gemm_kernel(const ushort_t* __restrict__ S,
                                                   const ushort_t* __restrict__ Abf,
                                                   const float* __restrict__ bias,
                                                   float* __restrict__ outb,
                                                   int d0, int Nch) {
  __shared__ ushort_t Al[NO * ALD];
  {
    const uint32_t* Ag = (const uint32_t*)Abf;
    uint32_t* Alw = (uint32_t*)Al;
    for (int e = threadIdx.x; e < (NO * KTOT) / 2; e += 256) {
      int row = e / 160, col = e % 160;
      Alw[row * (ALD / 2) + col] = Ag[e];
    }
  }
  __syncthreads();
  const int tid = threadIdx.x;
  const int lane = tid & 63, wi = tid >> 6;
  const int quad = lane >> 4, m15 = lane & 15;
  const int n_base = blockIdx.x * 128 + wi * 32;

  float4v acc[4][2];
#pragma unroll
  for (int mt = 0; mt < 4; ++mt)
#pragma unroll
    for (int nt = 0; nt < 2; ++nt) acc[mt][nt] = (float4v){0.f, 0.f, 0.f, 0.f};

#pragma unroll
  for (int ks = 0; ks < 10; ++ks) {
    short8v af[4];
#pragma unroll
    for (int mt = 0; mt < 4; ++mt)    // A[m = mt*16+m15][k = ks*32+quad*8 .. +7], 16B ds_read
      af[mt] = *(const short8v*)&Al[(mt * 16 + m15) * ALD + ks * 32 + quad * 8];
    short8v bfr[2];
#pragma unroll
    for (int nt = 0; nt < 2; ++nt) {  // B[k][n = n_base+nt*16+m15], k strided by Nch
      const ushort_t* sp = S + (size_t)(ks * 32 + quad * 8) * Nch + n_base + nt * 16 + m15;
      short8v v;
#pragma unroll
      for (int j = 0; j < 8; ++j) v[j] = (short)sp[(size_t)j * Nch];
      bfr[nt] = v;
    }
#pragma unroll
    for (int mt = 0; mt < 4; ++mt)
#pragma unroll
      for (int nt = 0; nt < 2; ++nt)
        acc[mt][nt] = __builtin_amdgcn_mfma_f32_16x16x32_bf16(af[mt], bfr[nt], acc[mt][nt], 0, 0, 0);
  }

  // C/D layout: col(n) = lane&15, row(m) = quad*4 + reg
  const int v_col = d0 * PLANE + n_base + m15;
#pragma unroll
  for (int mt = 0; mt < 4; ++mt) {
#pragma unroll
    for (int r = 0; r < 4; ++r) {
      int m = mt * 16 + quad * 4 + r;
      float bv = bias[m];
      float* op = outb + (size_t)m * V3 + v_col;
#pragma unroll
      for (int nt = 0; nt < 2; ++nt)
        op[nt * 16] = acc[mt][nt][r] + bv;
    }
  }
}

extern "C" void kernel_launch(void* const* d_in, const int* in_sizes, int n_in,
                              void* d_out, int out_size, void* d_ws, size_t ws_size,
                              hipStream_t stream) {
  const float* x    = (const float*)d_in[0];   // [2,32,1,48,48,48]
  const float* w    = (const float*)d_in[1];   // [64,32,1,1,1,10]
  const float* bias = (const float*)d_in[2];   // [64]
  float* out = (float*)d_out;                  // [2,64,1,48,48,48]

  ushort_t* Abf = (ushort_t*)d_ws;                          // 40960 B
  ushort_t* S   = (ushort_t*)((char*)d_ws + 65536);
  size_t avail = (ws_size > 65536) ? ws_size - 65536 : 0;
  int dlen = 12;                                            // d-chunk (multiple of 12)
  if (avail >= (size_t)48 * PLANE * KTOT * 2) dlen = 48;
  else if (avail >= (size_t)24 * PLANE * KTOT * 2) dlen = 24;

  prep_kernel<<<80, 256, 0, stream>>>(w, Abf);
  for (int b = 0; b < 2; ++b) {
    const float* xb = x + (size_t)b * NI * V3;
    float* outb = out + (size_t)b * NO * V3;
    for (int dd = 0; dd < 48; dd += dlen) {
      int Nch = dlen * PLANE;
      dim3 g1(9, dlen / 12, NI);
      shell_kernel<<<g1, 256, 0, stream>>>(xb, S, dd, Nch);
      gemm_kernel<<<Nch / 128, 256, 0, stream>>>(S, Abf, bias, outb, dd, Nch);
    }
  }
}